// Round 8
// baseline (399.846 us; speedup 1.0000x reference)
//
#include <hip/hip_runtime.h>
#include <stdint.h>

#define S_LEN 2048
#define BATCH 8
#define EMB   1024
#define GAMMA 0.5f

typedef unsigned short ushort_t;
typedef __attribute__((ext_vector_type(8))) short  short8;
typedef __attribute__((ext_vector_type(8))) unsigned short ushort8;
typedef __attribute__((ext_vector_type(4))) float  floatx4;

__device__ __forceinline__ ushort_t f2bf(float f) {
  uint32_t x = __float_as_uint(f);
  x += 0x7fffu + ((x >> 16) & 1u);   // round-to-nearest-even
  return (ushort_t)(x >> 16);
}

__device__ __forceinline__ void gl_lds16(const ushort_t* g, ushort_t* l) {
  __builtin_amdgcn_global_load_lds(
      (const __attribute__((address_space(1))) unsigned int*)g,
      (__attribute__((address_space(3))) unsigned int*)l, 16, 0, 0);
}

// ---------------------------------------------------------------------------
// 256x256-tile 8-wave pipelined NT bf16 GEMM core (C = A * B^T, K-contig).
// BK=64 as two 32-wide kslices; LDS regions (ushort offsets, per buffer):
//   As0 +0 | As1 +8192 | Bs0 +16384 | Bs1 +24576 ; regions 256r x 32 bf16.
// Double buffered = 128 KiB. Swizzle: slot ^= (row>>1)&3 on both the
// pre-swizzled global source and the ds_read address (R3, conflict-free).
//
// R8 = R7 (passing) + PRECOMPUTED swizzled LDS read offsets (HK tech #8):
// frag rows step by 16, and (q ^ (row>>1))&3 is invariant under row+=16
// (adds 8 to row>>1, == 0 mod 4). So ONE per-lane base per operand class:
//   aOff = ra*32 + ((q^(ra>>1))&3)*8 ; frag i at  region + aOff + i*512
//   bOff = rb*32 + ((q^(rb>>1))&3)*8 ; col m at   region + bOff + m*512
// -> all 24 ds_read addresses fold to base + immediate offset. Addresses are
// bit-identical to R7's lds_frag; sync/ledger untouched.
//
// Fences (R6/R7, ledger-verified): interval END =
//   [counted vmcnt if due][lgkmcnt(0)][s_barrier][""-asm memory wall]
// Prologue stages SEVEN halves incl. As1(1) (loop stages As1 only at kt+2).
// ---------------------------------------------------------------------------

#define MFMA_16(AR, B0, B1, J0, J1)                                            \
  _Pragma("unroll")                                                            \
  for (int i = 0; i < 8; ++i) {                                                \
    acc[i][J0] = __builtin_amdgcn_mfma_f32_16x16x32_bf16(AR[i], B0, acc[i][J0], 0, 0, 0); \
    acc[i][J1] = __builtin_amdgcn_mfma_f32_16x16x32_bf16(AR[i], B1, acc[i][J1], 0, 0, 0); \
  }

#define PHASE_END()                                                            \
  asm volatile("s_waitcnt lgkmcnt(0)" ::: "memory");                           \
  __builtin_amdgcn_s_barrier();                                                \
  asm volatile("" ::: "memory");

__device__ __forceinline__ void gemm8_core(
    const ushort_t* __restrict__ A, const ushort_t* __restrict__ B,
    int lda, int ldb, int K, ushort_t* smem, floatx4 (&acc)[8][4])
{
  const int tid = threadIdx.x;
  const int wave = tid >> 6, lane = tid & 63;
  const int wm = wave >> 2, wn = wave & 3;      // 2 (M) x 4 (N) wave grid
  const int lr = lane & 15, q = lane >> 4;
  const int NT = K >> 6;
  const int ra = wm * 128 + lr;   // wave's A-row base
  const int rb = wn * 64 + lr;    // wave's B-row base
  const int r4 = lane >> 2;
  const int slot = (lane & 3) ^ ((r4 >> 1) & 3);   // source pre-swizzle
  ushort_t* const lw = smem + wave * 1024;         // wave's slice of a region

  // Precomputed swizzled LDS read bases (ushort units); frag i -> +i*512.
  const int aOff = ra * 32 + (((q ^ (ra >> 1)) & 3) << 3);
  const int bOff = rb * 32 + (((q ^ (rb >> 1)) & 3) << 3);

  // Hoisted per-lane global stage pointers; inner loop adds 32-bit koff.
  const ushort_t* pA0 = A + (size_t)(wave * 32 + r4) * lda + slot * 8;
  const ushort_t* pA1 = pA0 + (size_t)16 * lda;
  const ushort_t* pB0 = B + (size_t)(wave * 32 + r4) * ldb + slot * 8;
  const ushort_t* pB1 = pB0 + (size_t)16 * ldb;

  auto stA = [&](int regionOff, int koff) {
    gl_lds16(pA0 + koff, lw + regionOff);
    gl_lds16(pA1 + koff, lw + regionOff + 512);
  };
  auto stB = [&](int regionOff, int koff) {
    gl_lds16(pB0 + koff, lw + regionOff);
    gl_lds16(pB1 + koff, lw + regionOff + 512);
  };

  // Prologue: SEVEN halves = all of kt0 + As0(1),Bs0(1),As1(1); drain kt0 (8).
  stA(0, 0);      stB(16384, 0);
  stA(8192, 32);  stB(24576, 32);
  stA(32768, 64); stB(49152, 64);
  stA(40960, 96);                                   // As1(1) — loop never stages it
  asm volatile("s_waitcnt vmcnt(6)" ::: "memory");  // keep As0/Bs0/As1(1)
  __builtin_amdgcn_s_barrier();
  asm volatile("" ::: "memory");

  short8 ar[8], ar2[8], b0, b1, t0, t1, u0, u1;
  {
    const ushort_t* pa = smem + aOff;
    const ushort_t* pb = smem + 16384 + bOff;
#pragma unroll
    for (int i = 0; i < 8; ++i) ar[i] = *(const short8*)(pa + i * 512);
    b0 = *(const short8*)(pb);
    b1 = *(const short8*)(pb + 512);
  }

  for (int kt = 0; kt < NT; ++kt) {
    const int bo = (kt & 1) * 32768;
    const int bn = bo ^ 32768;
    const ushort_t* const curA0 = smem + bo + aOff;
    const ushort_t* const curA1 = smem + bo + 8192 + aOff;
    const ushort_t* const curB0 = smem + bo + 16384 + bOff;
    const ushort_t* const curB1 = smem + bo + 24576 + bOff;
    const ushort_t* const nxtA0 = smem + bn + aOff;
    const ushort_t* const nxtB0 = smem + bn + 16384 + bOff;
    const bool s1 = (kt + 1) < NT, s2 = (kt + 2) < NT;
    const int k1 = (kt + 1) << 6, k2 = (kt + 2) << 6;

    // ---- I_0: reads {Bs0 m2/m3, As1 0..3}; stage Bs1(kt+1); MFMA s0 nf01
    t0 = *(const short8*)(curB0 + 1024);
    t1 = *(const short8*)(curB0 + 1536);
#pragma unroll
    for (int i = 0; i < 4; ++i) ar2[i] = *(const short8*)(curA1 + i * 512);
    if (s1) stB(bn + 24576, k1 + 32);
    __builtin_amdgcn_s_setprio(1);
    MFMA_16(ar, b0, b1, 0, 1)
    __builtin_amdgcn_s_setprio(0);
    PHASE_END()

    // ---- I_1: reads {As1 4..7, Bs1 m0/m1}; stage As0(kt+2); MFMA s0 nf23
#pragma unroll
    for (int i = 4; i < 8; ++i) ar2[i] = *(const short8*)(curA1 + i * 512);
    u0 = *(const short8*)(curB1);
    u1 = *(const short8*)(curB1 + 512);
    if (s2) stA(bo, k2);
    __builtin_amdgcn_s_setprio(1);
    MFMA_16(ar, t0, t1, 2, 3)
    __builtin_amdgcn_s_setprio(0);
    PHASE_END()

    // ---- I_2: reads {Bs1 m2/m3}; stage Bs0(kt+2); MFMA s1 nf01; vmcnt(4)
    t0 = *(const short8*)(curB1 + 1024);
    t1 = *(const short8*)(curB1 + 1536);
    if (s2) stB(bo + 16384, k2);
    __builtin_amdgcn_s_setprio(1);
    MFMA_16(ar2, u0, u1, 0, 1)
    __builtin_amdgcn_s_setprio(0);
    if (s2)      { asm volatile("s_waitcnt vmcnt(4)" ::: "memory"); }
    else if (s1) { asm volatile("s_waitcnt vmcnt(0)" ::: "memory"); }
    PHASE_END()

    // ---- I_3: reads next-kt {As0 x8, Bs0 m0/m1} from nxt; stage As1(kt+2); MFMA s1 nf23
    if (s1) {
#pragma unroll
      for (int i = 0; i < 8; ++i) ar[i] = *(const short8*)(nxtA0 + i * 512);
      b0 = *(const short8*)(nxtB0);
      b1 = *(const short8*)(nxtB0 + 512);
    }
    if (s2) stA(bo + 8192, k2 + 32);
    __builtin_amdgcn_s_setprio(1);
    MFMA_16(ar2, t0, t1, 2, 3)
    __builtin_amdgcn_s_setprio(0);
    PHASE_END()
  }
}

// ---------- quantize / pack ----------
__global__ __launch_bounds__(256) void k_quant_x(const float* __restrict__ X,
                                                 ushort_t* __restrict__ Xb) {
  size_t i = ((size_t)blockIdx.x * 256 + threadIdx.x) * 4;
  float4 v = *(const float4*)(X + i);
  *(ushort4*)(Xb + i) = make_ushort4(f2bf(v.x), f2bf(v.y), f2bf(v.z), f2bf(v.w));
}

__global__ __launch_bounds__(256) void k_quant_w(
    const float* __restrict__ Wq, const float* __restrict__ Wk,
    const float* __restrict__ Wv, ushort_t* __restrict__ W) {
  size_t i = ((size_t)blockIdx.x * 256 + threadIdx.x) * 4;
  int row = (int)(i >> 10), col = (int)(i & 1023);
  int sel = row >> 10, sr = row & 1023;
  const float* src = sel == 0 ? Wq : (sel == 1 ? Wk : Wv);
  float4 v = *(const float4*)(src + (size_t)sr * 1024 + col);
  *(ushort4*)(W + i) = make_ushort4(f2bf(v.x), f2bf(v.y), f2bf(v.z), f2bf(v.w));
}

__global__ __launch_bounds__(256) void k_bias_zero(
    const float* __restrict__ bq, const float* __restrict__ bk,
    const float* __restrict__ bv, float* __restrict__ bias,
    float* __restrict__ q2, float* __restrict__ k2, float* __restrict__ rsum) {
  int i = blockIdx.x * 256 + threadIdx.x;
  if (i < 1024)       bias[i] = bq[i];
  else if (i < 2048)  bias[i] = bk[i - 1024];
  else if (i < 3072)  bias[i] = bv[i - 2048];
  if (i < BATCH * S_LEN) { q2[i] = 0.f; k2[i] = 0.f; rsum[i] = 0.f; }
}

// ---------- GEMM 1: QKV projection (M=16384, N=3072, K=1024) ----------
__global__ __launch_bounds__(512, 2) void k_gemm_qkv(
    const ushort_t* __restrict__ Xb, const ushort_t* __restrict__ W,
    const float* __restrict__ bias,
    ushort_t* __restrict__ Q, ushort_t* __restrict__ Kp, ushort_t* __restrict__ V,
    float* __restrict__ q2, float* __restrict__ k2) {
  __shared__ __attribute__((aligned(16))) ushort_t smem[65536];
  // XCD swizzle (T1): lin%8 = XCD -> give each XCD 8 consecutive mt panels
  // (4 MB of X, L2-resident; X fetched once per XCD), nt sweeps slowest.
  const int lin = blockIdx.x + (blockIdx.y << 6);        // 0..767
  const int mt_i = (lin & 7) * 8 + ((lin >> 3) & 7);     // 0..63
  const int nt_i = lin >> 6;                             // 0..11
  const int mt = mt_i * 256, nt = nt_i * 256;
  floatx4 acc[8][4];
  const floatx4 z = {0.f, 0.f, 0.f, 0.f};
#pragma unroll
  for (int i = 0; i < 8; ++i)
#pragma unroll
    for (int j = 0; j < 4; ++j) acc[i][j] = z;

  gemm8_core(Xb + (size_t)mt * EMB, W + (size_t)nt * EMB, EMB, EMB, EMB, smem, acc);

  const int lane = threadIdx.x & 63, wave = threadIdx.x >> 6;
  const int wm = wave >> 2, wn = wave & 3;
  const int lr = lane & 15, q = lane >> 4;
  const int which = nt >> 10;        // 0=q 1=k 2=v  (256 | 1024 so no straddle)
  const int nc0 = nt & 1023;
  ushort_t* dst = which == 0 ? Q : (which == 1 ? Kp : V);
  float* sq = which == 0 ? q2 : k2;
  float bv4[4];
#pragma unroll
  for (int j = 0; j < 4; ++j) bv4[j] = bias[nt + wn * 64 + j * 16 + lr];

#pragma unroll
  for (int i = 0; i < 8; ++i) {
#pragma unroll
    for (int r = 0; r < 4; ++r) {
      const int g = mt + wm * 128 + i * 16 + q * 4 + r;
      const int t = g >> 3, b = g & 7;
      float ss = 0.f;
#pragma unroll
      for (int j = 0; j < 4; ++j) {
        const float val = acc[i][j][r] + bv4[j];
        dst[(size_t)(b * S_LEN + t) * EMB + nc0 + wn * 64 + j * 16 + lr] = f2bf(val);
        ss += val * val;
      }
      if (which < 2) {
        ss += __shfl_xor(ss, 1);
        ss += __shfl_xor(ss, 2);
        ss += __shfl_xor(ss, 4);
        ss += __shfl_xor(ss, 8);
        if (lr == 0) atomicAdd(&sq[b * S_LEN + t], ss);
      }
    }
  }
}

// ---------- transpose V[b][j][e] -> Vt[b][e][j] ----------
__global__ __launch_bounds__(256) void k_transpose(const ushort_t* __restrict__ V,
                                                   ushort_t* __restrict__ Vt) {
  __shared__ ushort_t tile[64][72];
  const int b = blockIdx.z, j0 = blockIdx.x * 64, e0 = blockIdx.y * 64;
  const ushort_t* src = V + ((size_t)b * S_LEN + j0) * EMB + e0;
  const int tid = threadIdx.x;
#pragma unroll
  for (int rep = 0; rep < 2; ++rep) {
    const int lin = rep * 256 + tid;
    const int j = lin >> 3, e8 = (lin & 7) * 8;
    *(uint4*)&tile[j][e8] = *(const uint4*)(src + (size_t)j * EMB + e8);
  }
  __syncthreads();
  ushort_t* dst = Vt + ((size_t)b * EMB + e0) * S_LEN + j0;
#pragma unroll
  for (int rep = 0; rep < 2; ++rep) {
    const int lin = rep * 256 + tid;
    const int e = lin >> 3, j8 = (lin & 7) * 8;
    ushort8 o;
#pragma unroll
    for (int m = 0; m < 8; ++m) o[m] = tile[j8 + m][e];
    *(ushort8*)(dst + (size_t)e * S_LEN + j8) = o;
  }
}

// ---------- GEMM 2: logits + exp (per batch: 2048 x 2048 x 1024) ----------
__global__ __launch_bounds__(512, 2) void k_logits(
    const ushort_t* __restrict__ Q, const ushort_t* __restrict__ Kp,
    const float* __restrict__ q2, const float* __restrict__ k2,
    ushort_t* __restrict__ P, float* __restrict__ rsum) {
  __shared__ __attribute__((aligned(16))) ushort_t smem[65536];
  // XCD swizzle: pin each batch to one XCD (Q/K panels L2-cycled per XCD).
  const int lin = blockIdx.x + (blockIdx.y << 3) + (blockIdx.z << 6);  // 0..511
  const int b = lin & 7;
  const int seq = lin >> 3;                    // 0..63
  const int mt = (seq & 7) * 256, nt = (seq >> 3) * 256;
  floatx4 acc[8][4];
  const floatx4 z = {0.f, 0.f, 0.f, 0.f};
#pragma unroll
  for (int i = 0; i < 8; ++i)
#pragma unroll
    for (int j = 0; j < 4; ++j) acc[i][j] = z;

  gemm8_core(Q + ((size_t)b * S_LEN + mt) * EMB,
             Kp + ((size_t)b * S_LEN + nt) * EMB, EMB, EMB, EMB, smem, acc);

  const int lane = threadIdx.x & 63, wave = threadIdx.x >> 6;
  const int wm = wave >> 2, wn = wave & 3;
  const int lr = lane & 15, q = lane >> 4;
  float k2v[4];
#pragma unroll
  for (int j = 0; j < 4; ++j) k2v[j] = k2[b * S_LEN + nt + wn * 64 + j * 16 + lr];

#pragma unroll
  for (int i = 0; i < 8; ++i) {
#pragma unroll
    for (int r = 0; r < 4; ++r) {
      const int t = mt + wm * 128 + i * 16 + q * 4 + r;
      const float q2v = q2[b * S_LEN + t];
      float ss = 0.f;
#pragma unroll
      for (int j = 0; j < 4; ++j) {
        float d2 = q2v + k2v[j] - 2.f * acc[i][j][r];
        d2 = fmaxf(d2, 0.f);
        const float p = __expf(-GAMMA * d2);
        P[((size_t)b * S_LEN + t) * S_LEN + nt + wn * 64 + j * 16 + lr] = f2bf(p);
        ss += p;
      }
      ss += __shfl_xor(ss, 1);
      ss += __shfl_xor(ss, 2);
      ss += __shfl_xor(ss, 4);
      ss += __shfl_xor(ss, 8);
      if (lr == 0) atomicAdd(&rsum[b * S_LEN + t], ss);
    }
  }
}

// ---------- GEMM 3: O = (P @ V) / rowsum (per batch: 2048 x 1024 x 2048) ----------
__global__ __launch_bounds__(512, 2) void k_out(
    const ushort_t* __restrict__ P, const ushort_t* __restrict__ Vt,
    const float* __restrict__ rsum, float* __restrict__ out) {
  __shared__ __attribute__((aligned(16))) ushort_t smem[65536];
  // XCD swizzle: batch-per-XCD (Vt[b] = 4 MB, L2-resident per XCD).
  const int lin = blockIdx.x + (blockIdx.y << 3) + (blockIdx.z << 5);  // 0..255
  const int b = lin & 7;
  const int seq = lin >> 3;                    // 0..31
  const int mt = (seq & 7) * 256, nt = (seq >> 3) * 256;
  floatx4 acc[8][4];
  const floatx4 z = {0.f, 0.f, 0.f, 0.f};
#pragma unroll
  for (int i = 0; i < 8; ++i)
#pragma unroll
    for (int j = 0; j < 4; ++j) acc[i][j] = z;

  gemm8_core(P + ((size_t)b * S_LEN + mt) * S_LEN,
             Vt + ((size_t)b * EMB + nt) * S_LEN, S_LEN, S_LEN, S_LEN, smem, acc);

  const int lane = threadIdx.x & 63, wave = threadIdx.x >> 6;
  const int wm = wave >> 2, wn = wave & 3;
  const int lr = lane & 15, q = lane >> 4;
#pragma unroll
  for (int i = 0; i < 8; ++i) {
#pragma unroll
    for (int r = 0; r < 4; ++r) {
      const int t = mt + wm * 128 + i * 16 + q * 4 + r;
      const float rinv = 1.f / rsum[b * S_LEN + t];
#pragma unroll
      for (int j = 0; j < 4; ++j) {
        const int e = nt + wn * 64 + j * 16 + lr;
        out[((size_t)t * BATCH + b) * EMB + e] = acc[i][j][r] * rinv;
      }
    }
  }
}

extern "C" void kernel_launch(void* const* d_in, const int* in_sizes, int n_in,
                              void* d_out, int out_size, void* d_ws, size_t ws_size,
                              hipStream_t stream) {
  (void)in_sizes; (void)n_in; (void)out_size; (void)ws_size;
  const float* X  = (const float*)d_in[0];
  const float* Wq = (const float*)d_in[1];
  const float* bq = (const float*)d_in[2];
  const float* Wk = (const float*)d_in[3];
  const float* bk = (const float*)d_in[4];
  const float* Wv = (const float*)d_in[5];
  const float* bv = (const float*)d_in[6];
  float* out = (float*)d_out;
  char* ws = (char*)d_ws;

  // workspace layout (bytes); Xb aliases P (Xb dead before P is written)
  ushort_t* Q    = (ushort_t*)(ws + 0);           //  33,554,432
  ushort_t* Kp   = (ushort_t*)(ws + 33554432);    //  33,554,432
  ushort_t* V    = (ushort_t*)(ws + 67108864);    //  33,554,432
  ushort_t* Vt   = (ushort_t*)(ws + 100663296);   //  33,554,432
  ushort_t* P    = (ushort_t*)(ws + 134217728);   //  67,108,864
  ushort_t* Xb   = (ushort_t*)(ws + 134217728);   //  alias of P[0:33.5M]
  ushort_t* Wqkv = (ushort_t*)(ws + 201326592);   //   6,291,456
  float*    bias = (float*)(ws + 207618048);      //      12,288
  float*    q2   = (float*)(ws + 207630336);      //      65,536
  float*    k2   = (float*)(ws + 207695872);      //      65,536
  float*    rsum = (float*)(ws + 207761408);      //      65,536  -> total ~198 MiB

  k_quant_x <<<16384, 256, 0, stream>>>(X, Xb);
  k_quant_w <<<3072, 256, 0, stream>>>(Wq, Wk, Wv, Wqkv);
  k_bias_zero<<<64, 256, 0, stream>>>(bq, bk, bv, bias, q2, k2, rsum);
  k_gemm_qkv<<<dim3(64, 12), 512, 0, stream>>>(Xb, Wqkv, bias, Q, Kp, V, q2, k2);
  k_transpose<<<dim3(32, 16, 8), 256, 0, stream>>>(V, Vt);
  k_logits  <<<dim3(8, 8, 8), 512, 0, stream>>>(Q, Kp, q2, k2, P, rsum);
  k_out     <<<dim3(8, 4, 8), 512, 0, stream>>>(P, Vt, rsum, out);
}

// Round 11
// 377.626 us; speedup vs baseline: 1.0588x; 1.0588x over previous
//
#include <hip/hip_runtime.h>
#include <stdint.h>

#define S_LEN 2048
#define BATCH 8
#define EMB   1024
#define GAMMA 0.5f

typedef unsigned short ushort_t;
typedef __attribute__((ext_vector_type(8))) short  short8;
typedef __attribute__((ext_vector_type(8))) unsigned short ushort8;
typedef __attribute__((ext_vector_type(4))) float  floatx4;

__device__ __forceinline__ ushort_t f2bf(float f) {
  uint32_t x = __float_as_uint(f);
  x += 0x7fffu + ((x >> 16) & 1u);   // round-to-nearest-even
  return (ushort_t)(x >> 16);
}

__device__ __forceinline__ void gl_lds16(const ushort_t* g, ushort_t* l) {
  __builtin_amdgcn_global_load_lds(
      (const __attribute__((address_space(1))) unsigned int*)g,
      (__attribute__((address_space(3))) unsigned int*)l, 16, 0, 0);
}

// ---------------------------------------------------------------------------
// 256x256-tile 8-wave pipelined NT bf16 GEMM core (C = A * B^T, K-contig).
// BK=64 as two 32-wide kslices; LDS regions (ushort offsets, per buffer):
//   As0 +0 | As1 +8192 | Bs0 +16384 | Bs1 +24576 ; regions 256r x 32 bf16.
// Double buffered = 128 KiB. Swizzle: slot ^= (row>>1)&3 on both the
// pre-swizzled global source and the ds_read address (R3, conflict-free).
// R8 core (passing, 112 us qkv): precomputed swizzled read bases; weak
// fences; 7-half prologue incl. As1(1); counted vmcnt(4) at I_2.
//
// R11 = R10 resubmit (two consecutive container/broker failures; source
// never executed). V-tile layout re-verified: idx = b*8192 + e*32 +
// ((t>>3)^(e&3))*8 + (t&7); strides 16384/64/16 B all 16-aligned; XOR-chunk
// swizzle -> free 2-way banks; read inverse chunk=quarter^(e&3) is exact.
// ---------------------------------------------------------------------------

#define MFMA_16(AR, B0, B1, J0, J1)                                            \
  _Pragma("unroll")                                                            \
  for (int i = 0; i < 8; ++i) {                                                \
    acc[i][J0] = __builtin_amdgcn_mfma_f32_16x16x32_bf16(AR[i], B0, acc[i][J0], 0, 0, 0); \
    acc[i][J1] = __builtin_amdgcn_mfma_f32_16x16x32_bf16(AR[i], B1, acc[i][J1], 0, 0, 0); \
  }

#define PHASE_END()                                                            \
  asm volatile("s_waitcnt lgkmcnt(0)" ::: "memory");                           \
  __builtin_amdgcn_s_barrier();                                                \
  asm volatile("" ::: "memory");

__device__ __forceinline__ void gemm8_core(
    const ushort_t* __restrict__ A, const ushort_t* __restrict__ B,
    int lda, int ldb, int K, ushort_t* smem, floatx4 (&acc)[8][4])
{
  const int tid = threadIdx.x;
  const int wave = tid >> 6, lane = tid & 63;
  const int wm = wave >> 2, wn = wave & 3;      // 2 (M) x 4 (N) wave grid
  const int lr = lane & 15, q = lane >> 4;
  const int NT = K >> 6;
  const int ra = wm * 128 + lr;   // wave's A-row base
  const int rb = wn * 64 + lr;    // wave's B-row base
  const int r4 = lane >> 2;
  const int slot = (lane & 3) ^ ((r4 >> 1) & 3);   // source pre-swizzle
  ushort_t* const lw = smem + wave * 1024;         // wave's slice of a region

  // Precomputed swizzled LDS read bases (ushort units); frag i -> +i*512.
  const int aOff = ra * 32 + (((q ^ (ra >> 1)) & 3) << 3);
  const int bOff = rb * 32 + (((q ^ (rb >> 1)) & 3) << 3);

  // Hoisted per-lane global stage pointers; inner loop adds 32-bit koff.
  const ushort_t* pA0 = A + (size_t)(wave * 32 + r4) * lda + slot * 8;
  const ushort_t* pA1 = pA0 + (size_t)16 * lda;
  const ushort_t* pB0 = B + (size_t)(wave * 32 + r4) * ldb + slot * 8;
  const ushort_t* pB1 = pB0 + (size_t)16 * ldb;

  auto stA = [&](int regionOff, int koff) {
    gl_lds16(pA0 + koff, lw + regionOff);
    gl_lds16(pA1 + koff, lw + regionOff + 512);
  };
  auto stB = [&](int regionOff, int koff) {
    gl_lds16(pB0 + koff, lw + regionOff);
    gl_lds16(pB1 + koff, lw + regionOff + 512);
  };

  // Prologue: SEVEN halves = all of kt0 + As0(1),Bs0(1),As1(1); drain kt0 (8).
  stA(0, 0);      stB(16384, 0);
  stA(8192, 32);  stB(24576, 32);
  stA(32768, 64); stB(49152, 64);
  stA(40960, 96);                                   // As1(1) — loop never stages it
  asm volatile("s_waitcnt vmcnt(6)" ::: "memory");  // keep As0/Bs0/As1(1)
  __builtin_amdgcn_s_barrier();
  asm volatile("" ::: "memory");

  short8 ar[8], ar2[8], b0, b1, t0, t1, u0, u1;
  {
    const ushort_t* pa = smem + aOff;
    const ushort_t* pb = smem + 16384 + bOff;
#pragma unroll
    for (int i = 0; i < 8; ++i) ar[i] = *(const short8*)(pa + i * 512);
    b0 = *(const short8*)(pb);
    b1 = *(const short8*)(pb + 512);
  }

  for (int kt = 0; kt < NT; ++kt) {
    const int bo = (kt & 1) * 32768;
    const int bn = bo ^ 32768;
    const ushort_t* const curA1 = smem + bo + 8192 + aOff;
    const ushort_t* const curB0 = smem + bo + 16384 + bOff;
    const ushort_t* const curB1 = smem + bo + 24576 + bOff;
    const ushort_t* const nxtA0 = smem + bn + aOff;
    const ushort_t* const nxtB0 = smem + bn + 16384 + bOff;
    const bool s1 = (kt + 1) < NT, s2 = (kt + 2) < NT;
    const int k1 = (kt + 1) << 6, k2 = (kt + 2) << 6;

    // ---- I_0: reads {Bs0 m2/m3, As1 0..3}; stage Bs1(kt+1); MFMA s0 nf01
    t0 = *(const short8*)(curB0 + 1024);
    t1 = *(const short8*)(curB0 + 1536);
#pragma unroll
    for (int i = 0; i < 4; ++i) ar2[i] = *(const short8*)(curA1 + i * 512);
    if (s1) stB(bn + 24576, k1 + 32);
    __builtin_amdgcn_s_setprio(1);
    MFMA_16(ar, b0, b1, 0, 1)
    __builtin_amdgcn_s_setprio(0);
    PHASE_END()

    // ---- I_1: reads {As1 4..7, Bs1 m0/m1}; stage As0(kt+2); MFMA s0 nf23
#pragma unroll
    for (int i = 4; i < 8; ++i) ar2[i] = *(const short8*)(curA1 + i * 512);
    u0 = *(const short8*)(curB1);
    u1 = *(const short8*)(curB1 + 512);
    if (s2) stA(bo, k2);
    __builtin_amdgcn_s_setprio(1);
    MFMA_16(ar, t0, t1, 2, 3)
    __builtin_amdgcn_s_setprio(0);
    PHASE_END()

    // ---- I_2: reads {Bs1 m2/m3}; stage Bs0(kt+2); MFMA s1 nf01; vmcnt(4)
    t0 = *(const short8*)(curB1 + 1024);
    t1 = *(const short8*)(curB1 + 1536);
    if (s2) stB(bo + 16384, k2);
    __builtin_amdgcn_s_setprio(1);
    MFMA_16(ar2, u0, u1, 0, 1)
    __builtin_amdgcn_s_setprio(0);
    if (s2)      { asm volatile("s_waitcnt vmcnt(4)" ::: "memory"); }
    else if (s1) { asm volatile("s_waitcnt vmcnt(0)" ::: "memory"); }
    PHASE_END()

    // ---- I_3: reads next-kt {As0 x8, Bs0 m0/m1} from nxt; stage As1(kt+2); MFMA s1 nf23
    if (s1) {
#pragma unroll
      for (int i = 0; i < 8; ++i) ar[i] = *(const short8*)(nxtA0 + i * 512);
      b0 = *(const short8*)(nxtB0);
      b1 = *(const short8*)(nxtB0 + 512);
    }
    if (s2) stA(bo + 8192, k2 + 32);
    __builtin_amdgcn_s_setprio(1);
    MFMA_16(ar2, t0, t1, 2, 3)
    __builtin_amdgcn_s_setprio(0);
    PHASE_END()
  }
}

// ---------- merged prep: quant X, quant W, bias copy, zero accumulators ----
__global__ __launch_bounds__(256) void k_prep(
    const float* __restrict__ X, const float* __restrict__ Wq,
    const float* __restrict__ Wk, const float* __restrict__ Wv,
    const float* __restrict__ bq, const float* __restrict__ bk,
    const float* __restrict__ bv,
    ushort_t* __restrict__ Xb, ushort_t* __restrict__ W,
    float* __restrict__ bias,
    float* __restrict__ q2, float* __restrict__ k2, float* __restrict__ rsum) {
  const int blk = blockIdx.x;
  if (blk < 16384) {
    size_t i = ((size_t)blk * 256 + threadIdx.x) * 4;
    float4 v = *(const float4*)(X + i);
    *(ushort4*)(Xb + i) = make_ushort4(f2bf(v.x), f2bf(v.y), f2bf(v.z), f2bf(v.w));
  } else if (blk < 19456) {
    size_t i = ((size_t)(blk - 16384) * 256 + threadIdx.x) * 4;
    int row = (int)(i >> 10), col = (int)(i & 1023);
    int sel = row >> 10, sr = row & 1023;
    const float* src = sel == 0 ? Wq : (sel == 1 ? Wk : Wv);
    float4 v = *(const float4*)(src + (size_t)sr * 1024 + col);
    *(ushort4*)(W + i) = make_ushort4(f2bf(v.x), f2bf(v.y), f2bf(v.z), f2bf(v.w));
  } else {
    int i = (blk - 19456) * 256 + threadIdx.x;
    if (i < 1024)       bias[i] = bq[i];
    else if (i < 2048)  bias[i] = bk[i - 1024];
    else if (i < 3072)  bias[i] = bv[i - 2048];
    if (i < BATCH * S_LEN) { q2[i] = 0.f; k2[i] = 0.f; rsum[i] = 0.f; }
  }
}

// ---------- GEMM 1: QKV projection (M=16384, N=3072, K=1024) ----------
// V-blocks (which==2) write Vt DIRECTLY via LDS re-tile (k_transpose removed).
// LDS V-tile layout (halfwords): idx = b*8192 + e*32 + ((t>>3)^(e&3))*8 + (t&7)
//   b<8, e<256, t<32. Byte strides 16384/64/16 -> every ushort8 access is
//   16B-aligned; XOR-chunk swizzle -> 2 lanes per 4-bank group (free).
//   Total 65536 halfwords = exactly the 128 KiB GEMM smem, reused.
__global__ __launch_bounds__(512, 2) void k_gemm_qkv(
    const ushort_t* __restrict__ Xb, const ushort_t* __restrict__ W,
    const float* __restrict__ bias,
    ushort_t* __restrict__ Q, ushort_t* __restrict__ Kp, ushort_t* __restrict__ Vt,
    float* __restrict__ q2, float* __restrict__ k2) {
  __shared__ __attribute__((aligned(16))) ushort_t smem[65536];
  // XCD swizzle (T1): lin%8 = XCD -> each XCD gets 8 consecutive mt panels.
  const int lin = blockIdx.x + (blockIdx.y << 6);        // 0..767
  const int mt_i = (lin & 7) * 8 + ((lin >> 3) & 7);     // 0..63
  const int nt_i = lin >> 6;                             // 0..11
  const int mt = mt_i * 256, nt = nt_i * 256;
  floatx4 acc[8][4];
  const floatx4 z = {0.f, 0.f, 0.f, 0.f};
#pragma unroll
  for (int i = 0; i < 8; ++i)
#pragma unroll
    for (int j = 0; j < 4; ++j) acc[i][j] = z;

  gemm8_core(Xb + (size_t)mt * EMB, W + (size_t)nt * EMB, EMB, EMB, EMB, smem, acc);

  const int tid = threadIdx.x;
  const int lane = tid & 63, wave = tid >> 6;
  const int wm = wave >> 2, wn = wave & 3;
  const int lr = lane & 15, q = lane >> 4;
  const int which = nt >> 10;        // 0=q 1=k 2=v  (256 | 1024 so no straddle)
  const int nc0 = nt & 1023;

  if (which < 2) {
    ushort_t* dst = which == 0 ? Q : Kp;
    float* sq = which == 0 ? q2 : k2;
    float bv4[4];
#pragma unroll
    for (int j = 0; j < 4; ++j) bv4[j] = bias[nt + wn * 64 + j * 16 + lr];
#pragma unroll
    for (int i = 0; i < 8; ++i) {
#pragma unroll
      for (int r = 0; r < 4; ++r) {
        const int g = mt + wm * 128 + i * 16 + q * 4 + r;
        const int t = g >> 3, b = g & 7;
        float ss = 0.f;
#pragma unroll
        for (int j = 0; j < 4; ++j) {
          const float val = acc[i][j][r] + bv4[j];
          dst[(size_t)(b * S_LEN + t) * EMB + nc0 + wn * 64 + j * 16 + lr] = f2bf(val);
          ss += val * val;
        }
        ss += __shfl_xor(ss, 1);
        ss += __shfl_xor(ss, 2);
        ss += __shfl_xor(ss, 4);
        ss += __shfl_xor(ss, 8);
        if (lr == 0) atomicAdd(&sq[b * S_LEN + t], ss);
      }
    }
  } else {
    // V path: stage bf16 tile into LDS (transposed, swizzled), write Vt.
    // gemm8_core ended with PHASE_END (barrier) -> LDS reuse is safe.
    float bv4[4];
#pragma unroll
    for (int j = 0; j < 4; ++j) bv4[j] = bias[nt + wn * 64 + j * 16 + lr];
#pragma unroll
    for (int i = 0; i < 8; ++i) {
#pragma unroll
      for (int r = 0; r < 4; ++r) {
        const int l = wm * 128 + i * 16 + q * 4 + r;   // local row 0..255
        const int tl = l >> 3, b = l & 7;              // t-local 0..31, batch
#pragma unroll
        for (int j = 0; j < 4; ++j) {
          const int e = wn * 64 + j * 16 + lr;         // local col 0..255
          smem[b * 8192 + e * 32 + (((tl >> 3) ^ (e & 3)) << 3) + (tl & 7)] =
              f2bf(acc[i][j][r] + bv4[j]);
        }
      }
    }
    __syncthreads();
    const int tb = mt >> 3;                            // global t base (32 rows)
#pragma unroll
    for (int rep = 0; rep < 16; ++rep) {
      const int task = rep * 512 + tid;                // 0..8191
      const int quarter = task & 3;                    // 16B chunk of 64B t-run
      const int pr = task >> 2;                        // (b,e) pair 0..2047
      const int e = pr & 255, b = pr >> 8;
      const int chunk = quarter ^ (e & 3);             // inverse of write swizzle
      ushort8 vv = *(const ushort8*)(smem + b * 8192 + e * 32 + chunk * 8);
      *(ushort8*)(Vt + ((size_t)b * EMB + nc0 + e) * S_LEN + tb + quarter * 8) = vv;
    }
  }
}

// ---------- GEMM 2: logits + exp (per batch: 2048 x 2048 x 1024) ----------
__global__ __launch_bounds__(512, 2) void k_logits(
    const ushort_t* __restrict__ Q, const ushort_t* __restrict__ Kp,
    const float* __restrict__ q2, const float* __restrict__ k2,
    ushort_t* __restrict__ P, float* __restrict__ rsum) {
  __shared__ __attribute__((aligned(16))) ushort_t smem[65536];
  // XCD swizzle: pin each batch to one XCD (Q/K panels L2-cycled per XCD).
  const int lin = blockIdx.x + (blockIdx.y << 3) + (blockIdx.z << 6);  // 0..511
  const int b = lin & 7;
  const int seq = lin >> 3;                    // 0..63
  const int mt = (seq & 7) * 256, nt = (seq >> 3) * 256;
  floatx4 acc[8][4];
  const floatx4 z = {0.f, 0.f, 0.f, 0.f};
#pragma unroll
  for (int i = 0; i < 8; ++i)
#pragma unroll
    for (int j = 0; j < 4; ++j) acc[i][j] = z;

  gemm8_core(Q + ((size_t)b * S_LEN + mt) * EMB,
             Kp + ((size_t)b * S_LEN + nt) * EMB, EMB, EMB, EMB, smem, acc);

  const int lane = threadIdx.x & 63, wave = threadIdx.x >> 6;
  const int wm = wave >> 2, wn = wave & 3;
  const int lr = lane & 15, q = lane >> 4;
  float k2v[4];
#pragma unroll
  for (int j = 0; j < 4; ++j) k2v[j] = k2[b * S_LEN + nt + wn * 64 + j * 16 + lr];

#pragma unroll
  for (int i = 0; i < 8; ++i) {
#pragma unroll
    for (int r = 0; r < 4; ++r) {
      const int t = mt + wm * 128 + i * 16 + q * 4 + r;
      const float q2v = q2[b * S_LEN + t];
      float ss = 0.f;
#pragma unroll
      for (int j = 0; j < 4; ++j) {
        float d2 = q2v + k2v[j] - 2.f * acc[i][j][r];
        d2 = fmaxf(d2, 0.f);
        const float p = __expf(-GAMMA * d2);
        P[((size_t)b * S_LEN + t) * S_LEN + nt + wn * 64 + j * 16 + lr] = f2bf(p);
        ss += p;
      }
      ss += __shfl_xor(ss, 1);
      ss += __shfl_xor(ss, 2);
      ss += __shfl_xor(ss, 4);
      ss += __shfl_xor(ss, 8);
      if (lr == 0) atomicAdd(&rsum[b * S_LEN + t], ss);
    }
  }
}

// ---------- GEMM 3: O = (P @ V) / rowsum (per batch: 2048 x 1024 x 2048) ----------
__global__ __launch_bounds__(512, 2) void k_out(
    const ushort_t* __restrict__ P, const ushort_t* __restrict__ Vt,
    const float* __restrict__ rsum, float* __restrict__ out) {
  __shared__ __attribute__((aligned(16))) ushort_t smem[65536];
  // XCD swizzle: batch-per-XCD (Vt[b] = 4 MB, L2-resident per XCD).
  const int lin = blockIdx.x + (blockIdx.y << 3) + (blockIdx.z << 5);  // 0..255
  const int b = lin & 7;
  const int seq = lin >> 3;                    // 0..31
  const int mt = (seq & 7) * 256, nt = (seq >> 3) * 256;
  floatx4 acc[8][4];
  const floatx4 z = {0.f, 0.f, 0.f, 0.f};
#pragma unroll
  for (int i = 0; i < 8; ++i)
#pragma unroll
    for (int j = 0; j < 4; ++j) acc[i][j] = z;

  gemm8_core(P + ((size_t)b * S_LEN + mt) * S_LEN,
             Vt + ((size_t)b * EMB + nt) * S_LEN, S_LEN, S_LEN, S_LEN, smem, acc);

  const int lane = threadIdx.x & 63, wave = threadIdx.x >> 6;
  const int wm = wave >> 2, wn = wave & 3;
  const int lr = lane & 15, q = lane >> 4;
#pragma unroll
  for (int i = 0; i < 8; ++i) {
#pragma unroll
    for (int r = 0; r < 4; ++r) {
      const int t = mt + wm * 128 + i * 16 + q * 4 + r;
      const float rinv = 1.f / rsum[b * S_LEN + t];
#pragma unroll
      for (int j = 0; j < 4; ++j) {
        const int e = nt + wn * 64 + j * 16 + lr;
        out[((size_t)t * BATCH + b) * EMB + e] = acc[i][j][r] * rinv;
      }
    }
  }
}

extern "C" void kernel_launch(void* const* d_in, const int* in_sizes, int n_in,
                              void* d_out, int out_size, void* d_ws, size_t ws_size,
                              hipStream_t stream) {
  (void)in_sizes; (void)n_in; (void)out_size; (void)ws_size;
  const float* X  = (const float*)d_in[0];
  const float* Wq = (const float*)d_in[1];
  const float* bq = (const float*)d_in[2];
  const float* Wk = (const float*)d_in[3];
  const float* bk = (const float*)d_in[4];
  const float* Wv = (const float*)d_in[5];
  const float* bv = (const float*)d_in[6];
  float* out = (float*)d_out;
  char* ws = (char*)d_ws;

  // workspace layout (bytes); Xb aliases P (Xb dead before P is written)
  ushort_t* Q    = (ushort_t*)(ws + 0);           //  33,554,432
  ushort_t* Kp   = (ushort_t*)(ws + 33554432);    //  33,554,432
  ushort_t* Vt   = (ushort_t*)(ws + 100663296);   //  33,554,432 (V buf removed)
  ushort_t* P    = (ushort_t*)(ws + 134217728);   //  67,108,864
  ushort_t* Xb   = (ushort_t*)(ws + 134217728);   //  alias of P[0:33.5M]
  ushort_t* Wqkv = (ushort_t*)(ws + 201326592);   //   6,291,456
  float*    bias = (float*)(ws + 207618048);      //      12,288
  float*    q2   = (float*)(ws + 207630336);      //      65,536
  float*    k2   = (float*)(ws + 207695872);      //      65,536
  float*    rsum = (float*)(ws + 207761408);      //      65,536  -> total ~198 MiB

  k_prep    <<<19520, 256, 0, stream>>>(X, Wq, Wk, Wv, bq, bk, bv,
                                        Xb, Wqkv, bias, q2, k2, rsum);
  k_gemm_qkv<<<dim3(64, 12), 512, 0, stream>>>(Xb, Wqkv, bias, Q, Kp, Vt, q2, k2);
  k_logits  <<<dim3(8, 8, 8), 512, 0, stream>>>(Q, Kp, q2, k2, P, rsum);
  k_out     <<<dim3(8, 4, 8), 512, 0, stream>>>(P, Vt, rsum, out);
}